// Round 12
// baseline (174.192 us; speedup 1.0000x reference)
//
#include <hip/hip_runtime.h>
#include <hip/hip_bf16.h>

#define BATCH 32
#define SEQ   2048
#define EMB   1024
#define HS    64
#define BT    (BATCH*SEQ)   // 65536 rows

typedef short s16x4 __attribute__((ext_vector_type(4)));
typedef short s16x8 __attribute__((ext_vector_type(8)));
typedef float f32x4 __attribute__((ext_vector_type(4)));
using u16 = unsigned short;

static __device__ __forceinline__ short f2bf(float f) {
  __hip_bfloat16 h = __float2bfloat16(f);
  return *reinterpret_cast<short*>(&h);
}

#define MFMA __builtin_amdgcn_mfma_f32_16x16x32_bf16

// ---------------------------------------------------------------------------
// W -> bf16, transposed: Wt[n][k], n = w*64+h (Wk|Wq|Wv). 768 KB once.
// ---------------------------------------------------------------------------
__global__ __launch_bounds__(256) void wconv_kernel(
    const float* __restrict__ Wk, const float* __restrict__ Wq,
    const float* __restrict__ Wv, short* __restrict__ Wt)
{
  const int n = blockIdx.x;            // 0..191
  const int w = n >> 6, h = n & 63;
  const float* Wp = (w == 0) ? Wk : (w == 1) ? Wq : Wv;
  const int k0 = threadIdx.x * 4;
  s16x4 p;
  #pragma unroll
  for (int e = 0; e < 4; ++e) p[e] = f2bf(Wp[(size_t)(k0 + e) * HS + h]);
  *(s16x4*)(Wt + (size_t)n * EMB + k0) = p;
}

// ---------------------------------------------------------------------------
// Projection v3: 64x192 tile, BK=64, col-split waves. CHANGE vs v2: both the
// x float4s (HBM) and W fragments (L2) for step k+64 are prefetched into
// registers during step k's MFMA phase (issued right after barrier-2).
// __syncthreads' vmcnt(0) drain then lands a full compute phase after issue
// -> staging and MFMA phases have no exposed memory latency.
// ---------------------------------------------------------------------------
__global__ __launch_bounds__(256, 4) void proj_kernel(
    const float* __restrict__ x, const short* __restrict__ Wt,
    short* __restrict__ kb, short* __restrict__ qb, short* __restrict__ vt)
{
  __shared__ __align__(16) u16 xs[64][72];
  const int tid  = threadIdx.x;
  const int row0 = blockIdx.x * 64;
  const int w  = tid >> 6, l = tid & 63;
  const int lr = l & 15, lg = l >> 4;
  const int xrow = tid >> 4, xc4 = tid & 15;

  float4 xr[4];
  s16x8  bw[2][3];

#define PREFX(K0) do {                                                        \
    _Pragma("unroll") for (int i = 0; i < 4; ++i)                             \
      xr[i] = *(const float4*)(x + (size_t)(row0 + i*16 + xrow) * EMB + (K0) + xc4*4); \
  } while (0)
#define PREFW(K0) do {                                                        \
    _Pragma("unroll") for (int kk = 0; kk < 2; ++kk)                          \
      _Pragma("unroll") for (int n = 0; n < 3; ++n)                           \
        bw[kk][n] = *(const s16x8*)(Wt + (size_t)(w*48 + n*16 + lr) * EMB + (K0) + kk*32 + lg*8); \
  } while (0)

  f32x4 acc[4][3];
  #pragma unroll
  for (int m = 0; m < 4; ++m)
    #pragma unroll
    for (int n = 0; n < 3; ++n) acc[m][n] = f32x4{0.f, 0.f, 0.f, 0.f};

  PREFW(0);
  PREFX(0);
  #pragma unroll 1
  for (int k0 = 0; k0 < EMB; k0 += 64) {
    __syncthreads();                 // drains prefetched xr/bw (issued ~1 phase ago)
    #pragma unroll
    for (int i = 0; i < 4; ++i) {
      s16x4 p;
      p[0] = f2bf(xr[i].x); p[1] = f2bf(xr[i].y);
      p[2] = f2bf(xr[i].z); p[3] = f2bf(xr[i].w);
      *(s16x4*)&xs[i*16 + xrow][xc4 * 4] = p;
    }
    __syncthreads();
    s16x8 bwc[2][3];
    #pragma unroll
    for (int kk = 0; kk < 2; ++kk)
      #pragma unroll
      for (int n = 0; n < 3; ++n) bwc[kk][n] = bw[kk][n];
    if (k0 + 64 < EMB) { PREFW(k0 + 64); PREFX(k0 + 64); }
    #pragma unroll
    for (int kk = 0; kk < 2; ++kk) {
      s16x8 a[4];
      #pragma unroll
      for (int m = 0; m < 4; ++m)
        a[m] = *(const s16x8*)&xs[m*16 + lr][kk*32 + lg*8];
      #pragma unroll
      for (int m = 0; m < 4; ++m)
        #pragma unroll
        for (int n = 0; n < 3; ++n)
          acc[m][n] = MFMA(a[m], bwc[kk][n], acc[m][n], 0, 0, 0);
    }
  }
#undef PREFX
#undef PREFW

  // epilogue: C/D layout col=lane&15, row=lg*4+reg
  const int b  = row0 >> 11;
  const int t0 = row0 & 2047;
  #pragma unroll
  for (int m = 0; m < 4; ++m) {
    const int trow = m*16 + lg*4;
    #pragma unroll
    for (int n = 0; n < 3; ++n) {
      const int nbase = w*48 + n*16;
      const int wm = nbase >> 6;            // wave-uniform: 0=k,1=q,2=v
      const int h  = (nbase + lr) & 63;
      if (wm == 2) {
        s16x4 p;
        #pragma unroll
        for (int r = 0; r < 4; ++r) p[r] = f2bf(acc[m][n][r]);
        *(s16x4*)(vt + ((size_t)(b*64 + h)) * SEQ + t0 + trow) = p;
      } else {
        short* dst = (wm == 0) ? kb : qb;
        #pragma unroll
        for (int r = 0; r < 4; ++r)
          dst[(size_t)(row0 + trow + r) * HS + h] = f2bf(acc[m][n][r]);
      }
    }
  }
}

// ---------------------------------------------------------------------------
// Flash attention v8 = v7 (LDS-staged q/v, XOR swizzle, fixed-max softmax,
// ones-MFMA row-sum, LPT + XCD swizzle) + register prefetch of the NEXT
// j-tile's q/v issued right after barrier-2 -> the barrier-1 vmcnt drain
// lands a full QK/softmax/PV phase after issue (latency hidden).
// ---------------------------------------------------------------------------
__global__ __launch_bounds__(256, 4) void attn_kernel(
    const short* __restrict__ kb, const short* __restrict__ qb,
    const short* __restrict__ vt, float* __restrict__ out)
{
  __shared__ __align__(16) u16 q_s[64*64];
  __shared__ __align__(16) u16 v_s[64*64];
  __shared__ __align__(16) u16 P_lds[4][16][72];   // per-wave private
  const int bid = blockIdx.x;
  const int wg  = (bid & 7) * 128 + (bid >> 3);    // 128 blocks (4 batches)/XCD
  const int b   = wg >> 5;
  const int it  = 31 - (wg & 31);                  // heavy i-tiles first (LPT)
  const int tid = threadIdx.x;
  const int w   = tid >> 6;                        // 0..3 (16-row strip)
  const int lr  = tid & 15;
  const int lg  = (tid & 63) >> 4;
  const int iw0 = it * 64 + w * 16;
  const int srow = tid >> 3, sc8 = tid & 7;        // staging map
  const int sdst = srow * 64 + ((sc8 * 8) ^ ((srow & 7) << 3));

  const short* qbb = qb + (size_t)b * SEQ * HS;
  const short* vtb = vt + (size_t)b * 64 * SEQ;

  s16x8 rq0, rq1, rv0, rv1;
#define PREFQV(J0) do {                                                       \
    rq0 = *(const s16x8*)(qbb + (size_t)((J0) + srow) * HS + sc8*8);          \
    rq1 = *(const s16x8*)(qbb + (size_t)((J0) + srow + 32) * HS + sc8*8);     \
    rv0 = *(const s16x8*)(vtb + (size_t)srow * SEQ + (J0) + sc8*8);           \
    rv1 = *(const s16x8*)(vtb + (size_t)(srow + 32) * SEQ + (J0) + sc8*8);    \
  } while (0)

  s16x8 ones;
  #pragma unroll
  for (int e = 0; e < 8; ++e) ones[e] = (short)0x3F80;   // bf16 1.0

  s16x8 kfrag[2];
  {
    const short* kp = kb + ((size_t)(b*SEQ) + iw0 + lr) * HS + lg*8;
    kfrag[0] = *(const s16x8*)(kp);
    kfrag[1] = *(const s16x8*)(kp + 32);
  }

  f32x4 o[4];
  #pragma unroll
  for (int n = 0; n < 4; ++n) o[n] = f32x4{0.f, 0.f, 0.f, 0.f};
  f32x4 lac = f32x4{0.f, 0.f, 0.f, 0.f};

  PREFQV(0);
  #pragma unroll 1
  for (int jt = 0; jt <= it; ++jt) {
    __syncthreads();   // prev tile's reads done + drains prefetched rq/rv
    *(s16x8*)&q_s[sdst]        = rq0;
    *(s16x8*)&q_s[sdst + 2048] = rq1;
    *(s16x8*)&v_s[sdst]        = rv0;
    *(s16x8*)&v_s[sdst + 2048] = rv1;
    __syncthreads();
    if (jt < it) PREFQV((jt + 1) * 64);
    // ---- QK^T from LDS ----
    f32x4 sc[4];
    #pragma unroll
    for (int s = 0; s < 4; ++s) {
      const int row = s*16 + lr, base = row * 64, swz = (row & 7) << 3;
      s16x8 q0 = *(const s16x8*)&q_s[base + ((lg*8) ^ swz)];
      s16x8 q1 = *(const s16x8*)&q_s[base + ((32 + lg*8) ^ swz)];
      f32x4 z = f32x4{0.f, 0.f, 0.f, 0.f};
      z = MFMA(q0, kfrag[0], z, 0, 0, 0);
      z = MFMA(q1, kfrag[1], z, 0, 0, 0);
      sc[s] = z;
    }
    // ---- fixed-max softmax + pack + P->LDS (wave-private, no barrier) ----
    const bool diag = (jt == it);
    #pragma unroll
    for (int s = 0; s < 4; ++s) {
      s16x4 pk;
      #pragma unroll
      for (int r = 0; r < 4; ++r) {
        float e = __expf(fmaf(sc[s][r], 0.03125f, -4.0f));
        if (diag && (s*16 + lg*4 + r > w*16 + lr)) e = 0.f;
        pk[r] = f2bf(e);
      }
      *(s16x4*)&P_lds[w][lr][16*s + 4*lg] = pk;
    }
    s16x8 pA0 = *(const s16x8*)&P_lds[w][lr][8*lg];
    s16x8 pA1 = *(const s16x8*)&P_lds[w][lr][32 + 8*lg];
    // ---- PV + row-sum, v from LDS ----
    __builtin_amdgcn_s_setprio(1);
    #pragma unroll
    for (int n = 0; n < 4; ++n) {
      const int rowh = n*16 + lr, base = rowh * 64, swz = (rowh & 7) << 3;
      s16x8 v0 = *(const s16x8*)&v_s[base + ((lg*8) ^ swz)];
      s16x8 v1 = *(const s16x8*)&v_s[base + ((32 + lg*8) ^ swz)];
      o[n] = MFMA(pA0, v0, o[n], 0, 0, 0);
      o[n] = MFMA(pA1, v1, o[n], 0, 0, 0);
    }
    lac = MFMA(pA0, ones, lac, 0, 0, 0);
    lac = MFMA(pA1, ones, lac, 0, 0, 0);
    __builtin_amdgcn_s_setprio(0);
  }
#undef PREFQV

  // epilogue: o[n][r] = O[i=iw0+lg*4+r][h=n*16+lr]; lac[r] = row sum
  float inv[4];
  #pragma unroll
  for (int r = 0; r < 4; ++r) inv[r] = 1.f / lac[r];
  #pragma unroll
  for (int n = 0; n < 4; ++n)
    #pragma unroll
    for (int r = 0; r < 4; ++r)
      out[((size_t)(b*SEQ) + iw0 + lg*4 + r) * HS + n*16 + lr] = o[n][r] * inv[r];
}

extern "C" void kernel_launch(void* const* d_in, const int* in_sizes, int n_in,
                              void* d_out, int out_size, void* d_ws, size_t ws_size,
                              hipStream_t stream) {
  const float* x  = (const float*)d_in[0];
  const float* Wk = (const float*)d_in[1];
  const float* Wq = (const float*)d_in[2];
  const float* Wv = (const float*)d_in[3];
  float* out = (float*)d_out;
  const size_t PLANE = (size_t)BT * HS;          // 4M elements
  short* kb = (short*)d_ws;                      // bf16 [BT][64]
  short* qb = kb + PLANE;                        // bf16 [BT][64]
  short* vt = kb + 2*PLANE;                      // bf16 [B][64][SEQ]
  short* Wt = kb + 3*PLANE;                      // bf16 [192][1024]

  wconv_kernel<<<192, 256, 0, stream>>>(Wk, Wq, Wv, Wt);
  proj_kernel<<<BT/64, 256, 0, stream>>>(x, Wt, kb, qb, vt);
  attn_kernel<<<BATCH*(SEQ/64), 256, 0, stream>>>(kb, qb, vt, out);
}

// Round 13
// 144.081 us; speedup vs baseline: 1.2090x; 1.2090x over previous
//
#include <hip/hip_runtime.h>
#include <hip/hip_bf16.h>

#define BATCH 32
#define SEQ   2048
#define EMB   1024
#define HS    64
#define BT    (BATCH*SEQ)   // 65536 rows

typedef short s16x4 __attribute__((ext_vector_type(4)));
typedef short s16x8 __attribute__((ext_vector_type(8)));
typedef float f32x4 __attribute__((ext_vector_type(4)));
using u16 = unsigned short;

static __device__ __forceinline__ short f2bf(float f) {
  __hip_bfloat16 h = __float2bfloat16(f);
  return *reinterpret_cast<short*>(&h);
}

#define MFMA __builtin_amdgcn_mfma_f32_16x16x32_bf16

// ---------------------------------------------------------------------------
// W -> bf16, transposed: Wt[n][k], n = w*64+h (Wk|Wq|Wv). 768 KB once.
// ---------------------------------------------------------------------------
__global__ __launch_bounds__(256) void wconv_kernel(
    const float* __restrict__ Wk, const float* __restrict__ Wq,
    const float* __restrict__ Wv, short* __restrict__ Wt)
{
  const int n = blockIdx.x;            // 0..191
  const int w = n >> 6, h = n & 63;
  const float* Wp = (w == 0) ? Wk : (w == 1) ? Wq : Wv;
  const int k0 = threadIdx.x * 4;
  s16x4 p;
  #pragma unroll
  for (int e = 0; e < 4; ++e) p[e] = f2bf(Wp[(size_t)(k0 + e) * HS + h]);
  *(s16x4*)(Wt + (size_t)n * EMB + k0) = p;
}

// ---------------------------------------------------------------------------
// Projection v4: 64x192 tile, BK=64, col-split waves, DOUBLE-BUFFERED x LDS.
// One barrier per K-step (vs v2's two). Per step: issue W frags (L2) FIRST,
// then next-tile x float4s (HBM) -- vmcnt is in-order, so waiting for W
// leaves the x loads in flight under the whole MFMA phase. cvt+ds_write of
// the next tile happens after compute into xs[nxt]; no registers live
// across barriers -> ~115 VGPR, 4 blocks/CU.
// ---------------------------------------------------------------------------
__global__ __launch_bounds__(256, 4) void proj_kernel(
    const float* __restrict__ x, const short* __restrict__ Wt,
    short* __restrict__ kb, short* __restrict__ qb, short* __restrict__ vt)
{
  __shared__ __align__(16) u16 xs[2][64][72];
  const int tid  = threadIdx.x;
  const int row0 = blockIdx.x * 64;
  const int w  = tid >> 6, l = tid & 63;
  const int lr = l & 15, lg = l >> 4;
  const int xrow = tid >> 4, xc4 = tid & 15;   // 16 lanes/row staging map

  f32x4 acc[4][3];
  #pragma unroll
  for (int m = 0; m < 4; ++m)
    #pragma unroll
    for (int n = 0; n < 3; ++n) acc[m][n] = f32x4{0.f, 0.f, 0.f, 0.f};

  // prologue: stage tile 0 into xs[0]
  #pragma unroll
  for (int i = 0; i < 4; ++i) {
    float4 t = *(const float4*)(x + (size_t)(row0 + i*16 + xrow) * EMB + xc4 * 4);
    s16x4 p;
    p[0] = f2bf(t.x); p[1] = f2bf(t.y); p[2] = f2bf(t.z); p[3] = f2bf(t.w);
    *(s16x4*)&xs[0][i*16 + xrow][xc4 * 4] = p;
  }
  __syncthreads();

  #pragma unroll 1
  for (int k0 = 0; k0 < EMB; k0 += 64) {
    const int cur = (k0 >> 6) & 1, nxt = cur ^ 1;
    const bool more = (k0 + 64 < EMB);
    // W frags for THIS step -- issued first (L2-resident)
    s16x8 bw[2][3];
    #pragma unroll
    for (int kk = 0; kk < 2; ++kk)
      #pragma unroll
      for (int n = 0; n < 3; ++n)
        bw[kk][n] = *(const s16x8*)(Wt + (size_t)(w*48 + n*16 + lr) * EMB + k0 + kk*32 + lg*8);
    // next x tile (HBM) -- issued second, stays in flight through MFMA phase
    float4 xr[4];
    if (more) {
      #pragma unroll
      for (int i = 0; i < 4; ++i)
        xr[i] = *(const float4*)(x + (size_t)(row0 + i*16 + xrow) * EMB + k0 + 64 + xc4 * 4);
    }
    // MFMA from xs[cur] (waits: lgkm for ds_read, vmcnt(4) for bw only)
    #pragma unroll
    for (int kk = 0; kk < 2; ++kk) {
      s16x8 a[4];
      #pragma unroll
      for (int m = 0; m < 4; ++m)
        a[m] = *(const s16x8*)&xs[cur][m*16 + lr][kk*32 + lg*8];
      #pragma unroll
      for (int m = 0; m < 4; ++m)
        #pragma unroll
        for (int n = 0; n < 3; ++n)
          acc[m][n] = MFMA(a[m], bw[kk][n], acc[m][n], 0, 0, 0);
    }
    // write next tile into xs[nxt]
    if (more) {
      #pragma unroll
      for (int i = 0; i < 4; ++i) {
        s16x4 p;
        p[0] = f2bf(xr[i].x); p[1] = f2bf(xr[i].y);
        p[2] = f2bf(xr[i].z); p[3] = f2bf(xr[i].w);
        *(s16x4*)&xs[nxt][i*16 + xrow][xc4 * 4] = p;
      }
    }
    __syncthreads();   // single barrier: cur-reads done AND nxt-writes done
  }

  // epilogue: C/D layout col=lane&15, row=lg*4+reg
  const int b  = row0 >> 11;
  const int t0 = row0 & 2047;
  #pragma unroll
  for (int m = 0; m < 4; ++m) {
    const int trow = m*16 + lg*4;
    #pragma unroll
    for (int n = 0; n < 3; ++n) {
      const int nbase = w*48 + n*16;
      const int wm = nbase >> 6;            // wave-uniform: 0=k,1=q,2=v
      const int h  = (nbase + lr) & 63;
      if (wm == 2) {
        s16x4 p;
        #pragma unroll
        for (int r = 0; r < 4; ++r) p[r] = f2bf(acc[m][n][r]);
        *(s16x4*)(vt + ((size_t)(b*64 + h)) * SEQ + t0 + trow) = p;
      } else {
        short* dst = (wm == 0) ? kb : qb;
        #pragma unroll
        for (int r = 0; r < 4; ++r)
          dst[(size_t)(row0 + trow + r) * HS + h] = f2bf(acc[m][n][r]);
      }
    }
  }
}

// ---------------------------------------------------------------------------
// Flash attention v7 (R11 form, verbatim): LDS-staged q/v tiles, XOR-swizzled
// ds_read_b128 fragments, fixed-max softmax, ones-MFMA row-sum, LPT + XCD
// swizzle, 4 blocks/CU.
// ---------------------------------------------------------------------------
__global__ __launch_bounds__(256, 4) void attn_kernel(
    const short* __restrict__ kb, const short* __restrict__ qb,
    const short* __restrict__ vt, float* __restrict__ out)
{
  __shared__ __align__(16) u16 q_s[64*64];
  __shared__ __align__(16) u16 v_s[64*64];
  __shared__ __align__(16) u16 P_lds[4][16][72];   // per-wave private
  const int bid = blockIdx.x;
  const int wg  = (bid & 7) * 128 + (bid >> 3);    // 128 blocks (4 batches)/XCD
  const int b   = wg >> 5;
  const int it  = 31 - (wg & 31);                  // heavy i-tiles first (LPT)
  const int tid = threadIdx.x;
  const int w   = tid >> 6;                        // 0..3 (16-row strip)
  const int lr  = tid & 15;
  const int lg  = (tid & 63) >> 4;
  const int iw0 = it * 64 + w * 16;

  const short* qbb = qb + (size_t)b * SEQ * HS;
  const short* vtb = vt + (size_t)b * 64 * SEQ;

  s16x8 ones;
  #pragma unroll
  for (int e = 0; e < 8; ++e) ones[e] = (short)0x3F80;   // bf16 1.0

  s16x8 kfrag[2];
  {
    const short* kp = kb + ((size_t)(b*SEQ) + iw0 + lr) * HS + lg*8;
    kfrag[0] = *(const s16x8*)(kp);
    kfrag[1] = *(const s16x8*)(kp + 32);
  }

  f32x4 o[4];
  #pragma unroll
  for (int n = 0; n < 4; ++n) o[n] = f32x4{0.f, 0.f, 0.f, 0.f};
  f32x4 lac = f32x4{0.f, 0.f, 0.f, 0.f};

  #pragma unroll 1
  for (int jt = 0; jt <= it; ++jt) {
    const int j0 = jt * 64;
    __syncthreads();   // previous tile's LDS reads complete before overwrite
    #pragma unroll
    for (int i = 0; i < 2; ++i) {
      const int idx = i * 256 + tid;
      const int row = idx >> 3, c8 = idx & 7;
      const int dst = row * 64 + ((c8 * 8) ^ ((row & 7) << 3));
      *(s16x8*)&q_s[dst] = *(const s16x8*)(qbb + (size_t)(j0 + row) * HS + c8 * 8);
      *(s16x8*)&v_s[dst] = *(const s16x8*)(vtb + (size_t)row * SEQ + j0 + c8 * 8);
    }
    __syncthreads();
    // ---- QK^T from LDS ----
    f32x4 sc[4];
    #pragma unroll
    for (int s = 0; s < 4; ++s) {
      const int row = s*16 + lr, base = row * 64, swz = (row & 7) << 3;
      s16x8 q0 = *(const s16x8*)&q_s[base + ((lg*8) ^ swz)];
      s16x8 q1 = *(const s16x8*)&q_s[base + ((32 + lg*8) ^ swz)];
      f32x4 z = f32x4{0.f, 0.f, 0.f, 0.f};
      z = MFMA(q0, kfrag[0], z, 0, 0, 0);
      z = MFMA(q1, kfrag[1], z, 0, 0, 0);
      sc[s] = z;
    }
    // ---- fixed-max softmax + pack + P->LDS (wave-private, no barrier) ----
    const bool diag = (jt == it);
    #pragma unroll
    for (int s = 0; s < 4; ++s) {
      s16x4 pk;
      #pragma unroll
      for (int r = 0; r < 4; ++r) {
        float e = __expf(fmaf(sc[s][r], 0.03125f, -4.0f));
        if (diag && (s*16 + lg*4 + r > w*16 + lr)) e = 0.f;
        pk[r] = f2bf(e);
      }
      *(s16x4*)&P_lds[w][lr][16*s + 4*lg] = pk;
    }
    s16x8 pA0 = *(const s16x8*)&P_lds[w][lr][8*lg];
    s16x8 pA1 = *(const s16x8*)&P_lds[w][lr][32 + 8*lg];
    // ---- PV + row-sum, v from LDS ----
    __builtin_amdgcn_s_setprio(1);
    #pragma unroll
    for (int n = 0; n < 4; ++n) {
      const int rowh = n*16 + lr, base = rowh * 64, swz = (rowh & 7) << 3;
      s16x8 v0 = *(const s16x8*)&v_s[base + ((lg*8) ^ swz)];
      s16x8 v1 = *(const s16x8*)&v_s[base + ((32 + lg*8) ^ swz)];
      o[n] = MFMA(pA0, v0, o[n], 0, 0, 0);
      o[n] = MFMA(pA1, v1, o[n], 0, 0, 0);
    }
    lac = MFMA(pA0, ones, lac, 0, 0, 0);
    lac = MFMA(pA1, ones, lac, 0, 0, 0);
    __builtin_amdgcn_s_setprio(0);
  }

  // epilogue: o[n][r] = O[i=iw0+lg*4+r][h=n*16+lr]; lac[r] = row sum
  float inv[4];
  #pragma unroll
  for (int r = 0; r < 4; ++r) inv[r] = 1.f / lac[r];
  #pragma unroll
  for (int n = 0; n < 4; ++n)
    #pragma unroll
    for (int r = 0; r < 4; ++r)
      out[((size_t)(b*SEQ) + iw0 + lg*4 + r) * HS + n*16 + lr] = o[n][r] * inv[r];
}

extern "C" void kernel_launch(void* const* d_in, const int* in_sizes, int n_in,
                              void* d_out, int out_size, void* d_ws, size_t ws_size,
                              hipStream_t stream) {
  const float* x  = (const float*)d_in[0];
  const float* Wk = (const float*)d_in[1];
  const float* Wq = (const float*)d_in[2];
  const float* Wv = (const float*)d_in[3];
  float* out = (float*)d_out;
  const size_t PLANE = (size_t)BT * HS;          // 4M elements
  short* kb = (short*)d_ws;                      // bf16 [BT][64]
  short* qb = kb + PLANE;                        // bf16 [BT][64]
  short* vt = kb + 2*PLANE;                      // bf16 [B][64][SEQ]
  short* Wt = kb + 3*PLANE;                      // bf16 [192][1024]

  wconv_kernel<<<192, 256, 0, stream>>>(Wk, Wq, Wv, Wt);
  proj_kernel<<<BT/64, 256, 0, stream>>>(x, Wt, kb, qb, vt);
  attn_kernel<<<BATCH*(SEQ/64), 256, 0, stream>>>(kb, qb, vt, out);
}

// Round 14
// 144.070 us; speedup vs baseline: 1.2091x; 1.0001x over previous
//
#include <hip/hip_runtime.h>
#include <hip/hip_bf16.h>

#define BATCH 32
#define SEQ   2048
#define EMB   1024
#define HS    64
#define BT    (BATCH*SEQ)   // 65536 rows

typedef short s16x4 __attribute__((ext_vector_type(4)));
typedef short s16x8 __attribute__((ext_vector_type(8)));
typedef float f32x4 __attribute__((ext_vector_type(4)));
typedef float f32x16 __attribute__((ext_vector_type(16)));
using u16 = unsigned short;
using u32 = unsigned int;

static __device__ __forceinline__ short f2bf(float f) {
  __hip_bfloat16 h = __float2bfloat16(f);
  return *reinterpret_cast<short*>(&h);
}
static __device__ __forceinline__ u32 pk2(float lo, float hi) {
  return (u32)(u16)f2bf(lo) | ((u32)(u16)f2bf(hi) << 16);
}
static __device__ __forceinline__ void pl32swap(u32& a, u32& b) {
  asm volatile("v_permlane32_swap_b32 %0, %1" : "+v"(a), "+v"(b));
}

#define MFMA   __builtin_amdgcn_mfma_f32_16x16x32_bf16
#define MFMA32 __builtin_amdgcn_mfma_f32_32x32x16_bf16

// ---------------------------------------------------------------------------
// W -> bf16, transposed: Wt[n][k], n = w*64+h (Wk|Wq|Wv). 768 KB once.
// ---------------------------------------------------------------------------
__global__ __launch_bounds__(256) void wconv_kernel(
    const float* __restrict__ Wk, const float* __restrict__ Wq,
    const float* __restrict__ Wv, short* __restrict__ Wt)
{
  const int n = blockIdx.x;            // 0..191
  const int w = n >> 6, h = n & 63;
  const float* Wp = (w == 0) ? Wk : (w == 1) ? Wq : Wv;
  const int k0 = threadIdx.x * 4;
  s16x4 p;
  #pragma unroll
  for (int e = 0; e < 4; ++e) p[e] = f2bf(Wp[(size_t)(k0 + e) * HS + h]);
  *(s16x4*)(Wt + (size_t)n * EMB + k0) = p;
}

// ---------------------------------------------------------------------------
// Projection (R11/R4 form, verbatim -- two pipelining attempts regressed).
// 64x192 tile, BK=64, col-split waves, W direct from L2, x staged via LDS.
// ---------------------------------------------------------------------------
__global__ __launch_bounds__(256, 4) void proj_kernel(
    const float* __restrict__ x, const short* __restrict__ Wt,
    short* __restrict__ kb, short* __restrict__ qb, short* __restrict__ vt)
{
  __shared__ __align__(16) u16 xs[64][72];
  const int tid  = threadIdx.x;
  const int row0 = blockIdx.x * 64;
  const int w  = tid >> 6, l = tid & 63;
  const int lr = l & 15, lg = l >> 4;

  f32x4 acc[4][3];
  #pragma unroll
  for (int m = 0; m < 4; ++m)
    #pragma unroll
    for (int n = 0; n < 3; ++n) acc[m][n] = f32x4{0.f, 0.f, 0.f, 0.f};

  for (int k0 = 0; k0 < EMB; k0 += 64) {
    s16x8 bw[2][3];
    #pragma unroll
    for (int kk = 0; kk < 2; ++kk)
      #pragma unroll
      for (int n = 0; n < 3; ++n)
        bw[kk][n] = *(const s16x8*)(Wt + (size_t)(w*48 + n*16 + lr) * EMB + k0 + kk*32 + lg*8);
    __syncthreads();
    #pragma unroll
    for (int i = 0; i < 4; ++i) {
      const int idx = i * 256 + tid;
      const int r = idx >> 4, c4 = idx & 15;
      float4 t = *(const float4*)(x + (size_t)(row0 + r) * EMB + k0 + c4 * 4);
      s16x4 p;
      p[0] = f2bf(t.x); p[1] = f2bf(t.y); p[2] = f2bf(t.z); p[3] = f2bf(t.w);
      *(s16x4*)&xs[r][c4 * 4] = p;
    }
    __syncthreads();
    #pragma unroll
    for (int kk = 0; kk < 2; ++kk) {
      s16x8 a[4];
      #pragma unroll
      for (int m = 0; m < 4; ++m)
        a[m] = *(const s16x8*)&xs[m*16 + lr][kk*32 + lg*8];
      #pragma unroll
      for (int m = 0; m < 4; ++m)
        #pragma unroll
        for (int n = 0; n < 3; ++n)
          acc[m][n] = MFMA(a[m], bw[kk][n], acc[m][n], 0, 0, 0);
    }
  }

  const int b  = row0 >> 11;
  const int t0 = row0 & 2047;
  #pragma unroll
  for (int m = 0; m < 4; ++m) {
    const int trow = m*16 + lg*4;
    #pragma unroll
    for (int n = 0; n < 3; ++n) {
      const int nbase = w*48 + n*16;
      const int wm = nbase >> 6;
      const int h  = (nbase + lr) & 63;
      if (wm == 2) {
        s16x4 p;
        #pragma unroll
        for (int r = 0; r < 4; ++r) p[r] = f2bf(acc[m][n][r]);
        *(s16x4*)(vt + ((size_t)(b*64 + h)) * SEQ + t0 + trow) = p;
      } else {
        short* dst = (wm == 0) ? kb : qb;
        #pragma unroll
        for (int r = 0; r < 4; ++r)
          dst[(size_t)(row0 + trow + r) * HS + h] = f2bf(acc[m][n][r]);
      }
    }
  }
}

// ---------------------------------------------------------------------------
// Flash attention v9: 32x32x16 MFMA (half the LDS bytes/FLOP of 16x16x32) +
// in-register P via cvt-pack + v_permlane32_swap_b32 (no P_lds roundtrip).
// Block = 4 waves x 32 i-rows = 128-row i-tile; 512 blocks, heavy-first LPT,
// XCD swizzle (4 batches/XCD L2). q/v tiles (8KB each) staged cooperatively,
// XOR-swizzled ds_read_b128 fragments. Fixed-max softmax (M=4; scores
// ~N(0,1/16)); row-sum via ones-B MFMA (lac rows match o rows).
// Layouts (A=q,B=k): S[reg r] = S[j=j0+sub*32+crow(r,hi)][i=iw0+(l&31)],
// crow(r,hi)=(r&3)+8*(r>>2)+4*hi. PV A-frag needs P[i=l&31][j=hi*8+e]:
// PA.w0/w1 = swap_first(pk(r0,r1),pk(r4,r5))/(pk(r2,r3),pk(r6,r7)),
// PA.w2/w3 = the swap_seconds; steps from r0-7 / r8-15 per subtile.
// ---------------------------------------------------------------------------
__global__ __launch_bounds__(256, 2) void attn_kernel(
    const short* __restrict__ kb, const short* __restrict__ qb,
    const short* __restrict__ vt, float* __restrict__ out)
{
  __shared__ __align__(16) u16 q_s[64*64];
  __shared__ __align__(16) u16 v_s[64*64];
  const int bid = blockIdx.x;
  const int wg  = (bid & 7) * 64 + (bid >> 3);   // 64 blocks (4 batches)/XCD
  const int b   = wg >> 4;
  const int it  = 15 - (wg & 15);                // heavy 128-row tiles first
  const int tid = threadIdx.x;
  const int w   = tid >> 6;                      // 0..3
  const int l   = tid & 63;
  const int li  = l & 31;
  const int hi  = l >> 5;
  const int iw0 = it * 128 + w * 32;
  const int jlast = 2 * it + (w >> 1);           // waves 0,1 skip final tile

  const short* qbb = qb + (size_t)b * SEQ * HS;
  const short* vtb = vt + (size_t)b * 64 * SEQ;

  s16x8 ones;
  #pragma unroll
  for (int e = 0; e < 8; ++e) ones[e] = (short)0x3F80;   // bf16 1.0

  // K fragments (B-operand): lane holds k[i=iw0+li][h=kst*16+hi*8+e]
  s16x8 kfrag[4];
  #pragma unroll
  for (int kst = 0; kst < 4; ++kst)
    kfrag[kst] = *(const s16x8*)(kb + ((size_t)(b*SEQ) + iw0 + li) * HS + kst*16 + hi*8);

  f32x16 o0, o1, lac;
  #pragma unroll
  for (int r = 0; r < 16; ++r) { o0[r] = 0.f; o1[r] = 0.f; lac[r] = 0.f; }

  #pragma unroll 1
  for (int jt = 0; jt <= 2*it + 1; ++jt) {
    const int j0 = jt * 64;
    __syncthreads();   // prev tile's LDS reads complete
    #pragma unroll
    for (int i2 = 0; i2 < 2; ++i2) {
      const int idx = i2 * 256 + tid;
      const int row = idx >> 3, c8 = idx & 7;
      const int dst = row * 64 + ((c8 * 8) ^ ((row & 7) << 3));
      *(s16x8*)&q_s[dst] = *(const s16x8*)(qbb + (size_t)(j0 + row) * HS + c8 * 8);
      *(s16x8*)&v_s[dst] = *(const s16x8*)(vtb + (size_t)row * SEQ + j0 + c8 * 8);
    }
    __syncthreads();
    if (jt > jlast) continue;   // after barriers: safe (no barrier below)

    // ---- QK^T: S = q (A) x k (B) ----
    f32x16 s0, s1;
    #pragma unroll
    for (int r = 0; r < 16; ++r) { s0[r] = 0.f; s1[r] = 0.f; }
    __builtin_amdgcn_s_setprio(1);
    #pragma unroll
    for (int kst = 0; kst < 4; ++kst) {
      const int cswz = (kst*16 + hi*8) ^ ((li & 7) << 3);
      s16x8 a0 = *(const s16x8*)&q_s[li * 64 + cswz];
      s16x8 a1 = *(const s16x8*)&q_s[(32 + li) * 64 + cswz];
      s0 = MFMA32(a0, kfrag[kst], s0, 0, 0, 0);
      s1 = MFMA32(a1, kfrag[kst], s1, 0, 0, 0);
    }
    __builtin_amdgcn_s_setprio(0);

    // ---- fixed-max softmax + in-register P assembly ----
    const bool maskT = (j0 + 63 > iw0);
    const int  ig    = iw0 + li;
    u32 pa[4][4];
    #pragma unroll
    for (int sub = 0; sub < 2; ++sub) {
      float p[16];
      #pragma unroll
      for (int r = 0; r < 16; ++r) {
        const float sv = sub ? s1[r] : s0[r];
        float e = __expf(fmaf(sv, 0.03125f, -4.0f));
        if (maskT) {
          const int jg = j0 + sub*32 + (r & 3) + 8*(r >> 2) + 4*hi;
          if (jg > ig) e = 0.f;
        }
        p[r] = e;
      }
      #pragma unroll
      for (int t = 0; t < 2; ++t) {
        u32 a0 = pk2(p[t*8+0], p[t*8+1]);
        u32 a1 = pk2(p[t*8+2], p[t*8+3]);
        u32 b0 = pk2(p[t*8+4], p[t*8+5]);
        u32 b1 = pk2(p[t*8+6], p[t*8+7]);
        pl32swap(a0, b0);
        pl32swap(a1, b1);
        pa[sub*2 + t][0] = a0; pa[sub*2 + t][1] = a1;
        pa[sub*2 + t][2] = b0; pa[sub*2 + t][3] = b1;
      }
    }

    // ---- PV + row-sum: O += P (A) x V (B), lac += P x ones ----
    __builtin_amdgcn_s_setprio(1);
    #pragma unroll
    for (int kst = 0; kst < 4; ++kst) {
      const int cswz = (kst*16 + hi*8) ^ ((li & 7) << 3);
      s16x8 v0 = *(const s16x8*)&v_s[li * 64 + cswz];
      s16x8 v1 = *(const s16x8*)&v_s[(32 + li) * 64 + cswz];
      s16x8 pf = *(const s16x8*)&pa[kst][0];
      o0  = MFMA32(pf, v0, o0, 0, 0, 0);
      o1  = MFMA32(pf, v1, o1, 0, 0, 0);
      lac = MFMA32(pf, ones, lac, 0, 0, 0);
    }
    __builtin_amdgcn_s_setprio(0);
  }

  // epilogue: o*[r] = O[i=iw0+crow(r,hi)][h=n*32+li]; lac[r] = rowsum(i)
  #pragma unroll
  for (int r = 0; r < 16; ++r) {
    const int row = iw0 + (r & 3) + 8*(r >> 2) + 4*hi;
    const float inv = 1.f / lac[r];
    float* op = out + ((size_t)(b*SEQ) + row) * HS + li;
    op[0]  = o0[r] * inv;
    op[32] = o1[r] * inv;
  }
}

extern "C" void kernel_launch(void* const* d_in, const int* in_sizes, int n_in,
                              void* d_out, int out_size, void* d_ws, size_t ws_size,
                              hipStream_t stream) {
  const float* x  = (const float*)d_in[0];
  const float* Wk = (const float*)d_in[1];
  const float* Wq = (const float*)d_in[2];
  const float* Wv = (const float*)d_in[3];
  float* out = (float*)d_out;
  const size_t PLANE = (size_t)BT * HS;          // 4M elements
  short* kb = (short*)d_ws;                      // bf16 [BT][64]
  short* qb = kb + PLANE;                        // bf16 [BT][64]
  short* vt = kb + 2*PLANE;                      // bf16 [B][64][SEQ]
  short* Wt = kb + 3*PLANE;                      // bf16 [192][1024]

  wconv_kernel<<<192, 256, 0, stream>>>(Wk, Wq, Wv, Wt);
  proj_kernel<<<BT/64, 256, 0, stream>>>(x, Wt, kb, qb, vt);
  attn_kernel<<<BATCH*(SEQ/128), 256, 0, stream>>>(kb, qb, vt, out);
}

// Round 16
// 129.278 us; speedup vs baseline: 1.3474x; 1.1144x over previous
//
#include <hip/hip_runtime.h>
#include <hip/hip_bf16.h>

#define BATCH 32
#define SEQ   2048
#define EMB   1024
#define HS    64
#define BT    (BATCH*SEQ)   // 65536 rows

typedef short s16x4 __attribute__((ext_vector_type(4)));
typedef short s16x8 __attribute__((ext_vector_type(8)));
typedef float f32x4 __attribute__((ext_vector_type(4)));
using u16 = unsigned short;

static __device__ __forceinline__ short f2bf(float f) {
  __hip_bfloat16 h = __float2bfloat16(f);
  return *reinterpret_cast<short*>(&h);
}
static __device__ __forceinline__ void gl_lds16(const void* g, void* l) {
  __builtin_amdgcn_global_load_lds(
      (const __attribute__((address_space(1))) unsigned int*)g,
      (__attribute__((address_space(3))) unsigned int*)l, 16, 0, 0);
}

#define MFMA __builtin_amdgcn_mfma_f32_16x16x32_bf16

// ---------------------------------------------------------------------------
// W -> bf16, transposed: Wt[n][k], n = w*64+h (Wk|Wq|Wv). 768 KB once.
// ---------------------------------------------------------------------------
__global__ __launch_bounds__(256) void wconv_kernel(
    const float* __restrict__ Wk, const float* __restrict__ Wq,
    const float* __restrict__ Wv, short* __restrict__ Wt)
{
  const int n = blockIdx.x;            // 0..191
  const int w = n >> 6, h = n & 63;
  const float* Wp = (w == 0) ? Wk : (w == 1) ? Wq : Wv;
  const int k0 = threadIdx.x * 4;
  s16x4 p;
  #pragma unroll
  for (int e = 0; e < 4; ++e) p[e] = f2bf(Wp[(size_t)(k0 + e) * HS + h]);
  *(s16x4*)(Wt + (size_t)n * EMB + k0) = p;
}

// ---------------------------------------------------------------------------
// Projection (R11/R4 form, verbatim -- two pipelining attempts regressed;
// leave it alone). 64x192 tile, BK=64, col-split waves, W direct from L2.
// ---------------------------------------------------------------------------
__global__ __launch_bounds__(256, 4) void proj_kernel(
    const float* __restrict__ x, const short* __restrict__ Wt,
    short* __restrict__ kb, short* __restrict__ qb, short* __restrict__ vt)
{
  __shared__ __align__(16) u16 xs[64][72];
  const int tid  = threadIdx.x;
  const int row0 = blockIdx.x * 64;
  const int w  = tid >> 6, l = tid & 63;
  const int lr = l & 15, lg = l >> 4;

  f32x4 acc[4][3];
  #pragma unroll
  for (int m = 0; m < 4; ++m)
    #pragma unroll
    for (int n = 0; n < 3; ++n) acc[m][n] = f32x4{0.f, 0.f, 0.f, 0.f};

  for (int k0 = 0; k0 < EMB; k0 += 64) {
    s16x8 bw[2][3];
    #pragma unroll
    for (int kk = 0; kk < 2; ++kk)
      #pragma unroll
      for (int n = 0; n < 3; ++n)
        bw[kk][n] = *(const s16x8*)(Wt + (size_t)(w*48 + n*16 + lr) * EMB + k0 + kk*32 + lg*8);
    __syncthreads();
    #pragma unroll
    for (int i = 0; i < 4; ++i) {
      const int idx = i * 256 + tid;
      const int r = idx >> 4, c4 = idx & 15;
      float4 t = *(const float4*)(x + (size_t)(row0 + r) * EMB + k0 + c4 * 4);
      s16x4 p;
      p[0] = f2bf(t.x); p[1] = f2bf(t.y); p[2] = f2bf(t.z); p[3] = f2bf(t.w);
      *(s16x4*)&xs[r][c4 * 4] = p;
    }
    __syncthreads();
    #pragma unroll
    for (int kk = 0; kk < 2; ++kk) {
      s16x8 a[4];
      #pragma unroll
      for (int m = 0; m < 4; ++m)
        a[m] = *(const s16x8*)&xs[m*16 + lr][kk*32 + lg*8];
      #pragma unroll
      for (int m = 0; m < 4; ++m)
        #pragma unroll
        for (int n = 0; n < 3; ++n)
          acc[m][n] = MFMA(a[m], bw[kk][n], acc[m][n], 0, 0, 0);
    }
  }

  const int b  = row0 >> 11;
  const int t0 = row0 & 2047;
  #pragma unroll
  for (int m = 0; m < 4; ++m) {
    const int trow = m*16 + lg*4;
    #pragma unroll
    for (int n = 0; n < 3; ++n) {
      const int nbase = w*48 + n*16;
      const int wm = nbase >> 6;
      const int h  = (nbase + lr) & 63;
      if (wm == 2) {
        s16x4 p;
        #pragma unroll
        for (int r = 0; r < 4; ++r) p[r] = f2bf(acc[m][n][r]);
        *(s16x4*)(vt + ((size_t)(b*64 + h)) * SEQ + t0 + trow) = p;
      } else {
        short* dst = (wm == 0) ? kb : qb;
        #pragma unroll
        for (int r = 0; r < 4; ++r)
          dst[(size_t)(row0 + trow + r) * HS + h] = f2bf(acc[m][n][r]);
      }
    }
  }
}

// ---------------------------------------------------------------------------
// Flash attention v10 = R11's 16x16 compute core + DOUBLE-BUFFERED q_s/v_s
// staged via global_load_lds (width=16, linear LDS dest; the XOR swizzle is
// applied to the GLOBAL source address -- pure permutation, bit-identical
// data). One barrier per tile: STAGE(jt+1) issued BEFORE compute(jt), so the
// barrier's vmcnt(0) drain lands a full compute phase after issue (T3
// minimal 2-phase). LDS 41 KB -> 3 blocks/CU (launch_bounds(256,3)).
// Fixed-max softmax, ones-MFMA row-sum, LPT + XCD swizzle unchanged.
// ---------------------------------------------------------------------------
__global__ __launch_bounds__(256, 3) void attn_kernel(
    const short* __restrict__ kb, const short* __restrict__ qb,
    const short* __restrict__ vt, float* __restrict__ out)
{
  __shared__ __align__(16) u16 q_s[2][4096];
  __shared__ __align__(16) u16 v_s[2][4096];
  __shared__ __align__(16) u16 P_lds[4][16][72];   // per-wave private
  const int bid = blockIdx.x;
  const int wg  = (bid & 7) * 128 + (bid >> 3);    // 128 blocks (4 batches)/XCD
  const int b   = wg >> 5;
  const int it  = 31 - (wg & 31);                  // heavy i-tiles first (LPT)
  const int tid = threadIdx.x;
  const int w   = tid >> 6;                        // 0..3 (16-row strip)
  const int lr  = tid & 15;
  const int lg  = (tid & 63) >> 4;
  const int iw0 = it * 64 + w * 16;

  const short* qbb = qb + (size_t)b * SEQ * HS;
  const short* vtb = vt + (size_t)b * 64 * SEQ;

  // staging geometry: 16B slot s = i2*256+tid; row = s>>3, c8 = s&7.
  // LDS linear dest (wave-uniform base + lane*16B); global col pre-swizzled.
  const int srow0 = (0*256 + tid) >> 3, sc80 = tid & 7;
  const int srow1 = (256 + tid) >> 3;
  const int gcol0 = (sc80 * 8) ^ ((srow0 & 7) << 3);
  const int gcol1 = (sc80 * 8) ^ ((srow1 & 7) << 3);

#define STAGE(BUF, J0) do {                                                    \
    u16* lq0 = &q_s[BUF][(w*64) * 8];                                          \
    u16* lv0 = &v_s[BUF][(w*64) * 8];                                          \
    u16* lq1 = &q_s[BUF][(256 + w*64) * 8];                                    \
    u16* lv1 = &v_s[BUF][(256 + w*64) * 8];                                    \
    gl_lds16(qbb + (size_t)((J0) + srow0) * HS + gcol0, lq0);                  \
    gl_lds16(vtb + (size_t)srow0 * SEQ + (J0) + gcol0, lv0);                   \
    gl_lds16(qbb + (size_t)((J0) + srow1) * HS + gcol1, lq1);                  \
    gl_lds16(vtb + (size_t)srow1 * SEQ + (J0) + gcol1, lv1);                   \
  } while (0)

  s16x8 ones;
  #pragma unroll
  for (int e = 0; e < 8; ++e) ones[e] = (short)0x3F80;   // bf16 1.0

  s16x8 kfrag[2];
  {
    const short* kp = kb + ((size_t)(b*SEQ) + iw0 + lr) * HS + lg*8;
    kfrag[0] = *(const s16x8*)(kp);
    kfrag[1] = *(const s16x8*)(kp + 32);
  }

  f32x4 o[4];
  #pragma unroll
  for (int n = 0; n < 4; ++n) o[n] = f32x4{0.f, 0.f, 0.f, 0.f};
  f32x4 lac = f32x4{0.f, 0.f, 0.f, 0.f};

  STAGE(0, 0);
  __syncthreads();   // prologue stage drained (one exposed latency)

  int cur = 0;
  #pragma unroll 1
  for (int jt = 0; jt <= it; ++jt) {
    if (jt < it) STAGE(cur ^ 1, (jt + 1) * 64);   // in flight through compute
    // ---- QK^T from q_s[cur] ----
    const u16* qsb = q_s[cur];
    const u16* vsb = v_s[cur];
    f32x4 sc[4];
    #pragma unroll
    for (int s = 0; s < 4; ++s) {
      const int row = s*16 + lr, base = row * 64, swz = (row & 7) << 3;
      s16x8 q0 = *(const s16x8*)&qsb[base + ((lg*8) ^ swz)];
      s16x8 q1 = *(const s16x8*)&qsb[base + ((32 + lg*8) ^ swz)];
      f32x4 z = f32x4{0.f, 0.f, 0.f, 0.f};
      z = MFMA(q0, kfrag[0], z, 0, 0, 0);
      z = MFMA(q1, kfrag[1], z, 0, 0, 0);
      sc[s] = z;
    }
    // ---- fixed-max softmax + pack + P->LDS (wave-private) ----
    const bool diag = (jt == it);
    #pragma unroll
    for (int s = 0; s < 4; ++s) {
      s16x4 pk;
      #pragma unroll
      for (int r = 0; r < 4; ++r) {
        float e = __expf(fmaf(sc[s][r], 0.03125f, -4.0f));
        if (diag && (s*16 + lg*4 + r > w*16 + lr)) e = 0.f;
        pk[r] = f2bf(e);
      }
      *(s16x4*)&P_lds[w][lr][16*s + 4*lg] = pk;
    }
    s16x8 pA0 = *(const s16x8*)&P_lds[w][lr][8*lg];
    s16x8 pA1 = *(const s16x8*)&P_lds[w][lr][32 + 8*lg];
    // ---- PV + row-sum from v_s[cur] ----
    __builtin_amdgcn_s_setprio(1);
    #pragma unroll
    for (int n = 0; n < 4; ++n) {
      const int rowh = n*16 + lr, base = rowh * 64, swz = (rowh & 7) << 3;
      s16x8 v0 = *(const s16x8*)&vsb[base + ((lg*8) ^ swz)];
      s16x8 v1 = *(const s16x8*)&vsb[base + ((32 + lg*8) ^ swz)];
      o[n] = MFMA(pA0, v0, o[n], 0, 0, 0);
      o[n] = MFMA(pA1, v1, o[n], 0, 0, 0);
    }
    lac = MFMA(pA0, ones, lac, 0, 0, 0);
    lac = MFMA(pA1, ones, lac, 0, 0, 0);
    __builtin_amdgcn_s_setprio(0);
    __syncthreads();   // drains next-tile stage + all reads of cur done
    cur ^= 1;
  }
#undef STAGE

  // epilogue: o[n][r] = O[i=iw0+lg*4+r][h=n*16+lr]; lac[r] = row sum
  float inv[4];
  #pragma unroll
  for (int r = 0; r < 4; ++r) inv[r] = 1.f / lac[r];
  #pragma unroll
  for (int n = 0; n < 4; ++n)
    #pragma unroll
    for (int r = 0; r < 4; ++r)
      out[((size_t)(b*SEQ) + iw0 + lg*4 + r) * HS + n*16 + lr] = o[n][r] * inv[r];
}

extern "C" void kernel_launch(void* const* d_in, const int* in_sizes, int n_in,
                              void* d_out, int out_size, void* d_ws, size_t ws_size,
                              hipStream_t stream) {
  const float* x  = (const float*)d_in[0];
  const float* Wk = (const float*)d_in[1];
  const float* Wq = (const float*)d_in[2];
  const float* Wv = (const float*)d_in[3];
  float* out = (float*)d_out;
  const size_t PLANE = (size_t)BT * HS;          // 4M elements
  short* kb = (short*)d_ws;                      // bf16 [BT][64]
  short* qb = kb + PLANE;                        // bf16 [BT][64]
  short* vt = kb + 2*PLANE;                      // bf16 [B][64][SEQ]
  short* Wt = kb + 3*PLANE;                      // bf16 [192][1024]

  wconv_kernel<<<192, 256, 0, stream>>>(Wk, Wq, Wv, Wt);
  proj_kernel<<<BT/64, 256, 0, stream>>>(x, Wt, kb, qb, vt);
  attn_kernel<<<BATCH*(SEQ/64), 256, 0, stream>>>(kb, qb, vt, out);
}